// Round 2
// baseline (1350.118 us; speedup 1.0000x reference)
//
#include <hip/hip_runtime.h>

// HMM forward (CgpHmmCell): B=512, T=4096, S=64, M=125.
// Round 19: R18 + PREFETCH DISTANCE 3-4 (four 8-row slots A,B,C,D).
// Model: BW-pinned step period P = 8KB/(6.3TB/s / 2048 waves) ~ 6.4k cyc;
// queueing latency at saturation ~ 12-13k cyc. R17's ping-pong coverage
// 2P ~ 13k == latency -> zero margin, every jitter stalls (274us ~ serial
// 190 extract + 93 scan). Four slots give coverage 3-4P ~ 19-26k cyc.
// Slot for ext-step e=8p+k is (k+1)&3 (compile-time: 8p%4==0). Refills
// issue in pairs at k%4==0 (A<-e+3, B<-e+4) and k%4==2 (C<-e+3, D<-e+4).
// Phase A runs the same 4-slot rotation distance-3 (4-unrolled group loop);
// its final issues j=17,18,19 ARE Phase B's preps e=0,1,2 (slot (e+1)&3
// lines up exactly). E-read moved to the consume section to keep the
// MFMA+ext VGPR peak window flat (+64 buf regs). __launch_bounds__(256,2)
// pins 2 waves/SIMD. Numerics identical to R18 (absmax 0.0): same loads,
// ext, MFMA order, 2^56 rescale, mass identity, chunk-0 exact I*E0
// override, one atomicAdd per wave. d_ws unused.

#define BATCH 512
#define T 4096
#define S 64
#define M 125
#define BMS 68     // BmL row stride in dwords: 68%32=4 -> 8 bank phases, 16B-aligned
#define NPACK 10   // 2 burn + 8 accumulate (chunk = 64 steps)
#define BURNP 2
#define WPB 4
#define RB 56.0f
#define SCALEF 7.205759403792794e16f   // 2^56

typedef __attribute__((ext_vector_type(8))) short bf16x8;
typedef __attribute__((ext_vector_type(4))) float f32x4;
typedef float f32x4u __attribute__((ext_vector_type(4), aligned(4)));  // 4-B-aligned vec4

union BFU { unsigned u[4]; bf16x8 v; };

__device__ __forceinline__ unsigned pk_trunc(float a, float b) {
    return (__float_as_uint(b) & 0xFFFF0000u) | (__float_as_uint(a) >> 16);
}
__device__ __forceinline__ unsigned pk_rne(float a, float b) {
    unsigned ua = __float_as_uint(a); ua += 0x7FFFu + ((ua >> 16) & 1u);
    unsigned ub = __float_as_uint(b); ub += 0x7FFFu + ((ub >> 16) & 1u);
    return (ub & 0xFFFF0000u) | (ua >> 16);
}

__global__ __launch_bounds__(256, 2) void hmm_fused(const float* __restrict__ x,
                                                    const float* __restrict__ Iv,
                                                    const float* __restrict__ A,
                                                    const float* __restrict__ Bm,
                                                    float* __restrict__ out) {
    __shared__ __align__(16) float BmL[M * BMS];               // 34000 B, stride-68 rows
    __shared__ __align__(16) float ILds[S];
    __shared__ unsigned long long ulds[WPB * 16 * NPACK];      // 5120 B

    const int tid = threadIdx.x, wv = tid >> 6, lane = tid & 63;
    const int s = lane & 15, g = lane >> 4;

    for (int i = tid; i < M * S; i += WPB * 64)
        BmL[(i >> 6) * BMS + (i & 63)] = Bm[i];
    if (tid < S) ILds[tid] = Iv[tid];
    __syncthreads();

    // A^T fragments under pi: slot (kf,g,j2,e) holds A[p0+e][16mt+s],
    // p0 = 32kf + 16*(j2>>1) + 4g + 2*(j2&1).
    BFU Af[4][2];
#pragma unroll
    for (int mt = 0; mt < 4; ++mt)
#pragma unroll
        for (int kf = 0; kf < 2; ++kf)
#pragma unroll
            for (int j2 = 0; j2 < 4; ++j2) {
                int p0 = 32 * kf + 16 * (j2 >> 1) + 4 * g + 2 * (j2 & 1);
                Af[mt][kf].u[j2] = pk_rne(A[(size_t)p0 * S + mt * 16 + s],
                                          A[(size_t)(p0 + 1) * S + mt * 16 + s]);
            }

    const int W = blockIdx.x * WPB + wv;   // 0..2047
    const int seq = W >> 2, wq = W & 3;    // 4 waves per sequence
    const float* xs = x + (size_t)seq * T * M;
    unsigned long long* myu = &ulds[wv * 16 * NPACK];
    const int base = wq * 1024;            // wave's first row (seq-relative)

    const int rel = lane & 31, hf = lane >> 5;
    const unsigned coff = (rel < 31) ? 4u * (unsigned)rel : 121u;  // dword in row

    f32x4u bA[8], bB[8], bC[8], bD[8];     // four 16-row slots, distance 3-4

    auto issue16 = [&](f32x4u (&bf)[8], int r0a, int r0b) {
#pragma unroll
        for (int j = 0; j < 4; ++j) {
            unsigned ra = (unsigned)((r0a + 2 * j + hf) * 125) + coff;
            unsigned rb = (unsigned)((r0b + 2 * j + hf) * 125) + coff;
            bf[j]     = *(const f32x4u*)&xs[ra];
            bf[4 + j] = *(const f32x4u*)&xs[rb];
        }
    };
    auto ext8 = [&](const f32x4u (&bf)[8], int b) -> unsigned long long {
        unsigned long long acc = 0;
#pragma unroll
        for (int j = 0; j < 4; ++j) {
            f32x4u v = bf[b * 4 + j];
            bool nz = (v.x != 0.f) || (v.y != 0.f) || (v.z != 0.f) || (v.w != 0.f);
            unsigned li = (v.x != 0.f) ? 0u : ((v.y != 0.f) ? 1u : ((v.z != 0.f) ? 2u : 3u));
            unsigned cand = coff + li;                 // dword index of first nz here
            unsigned long long m = __ballot(nz);       // one-hot => both halves nonzero
            unsigned l0 = (unsigned)__builtin_ctzll(m & 0xffffffffull);
            unsigned l1 = (unsigned)__builtin_ctzll(m >> 32);
            unsigned o0 = __builtin_amdgcn_readlane(cand, l0);        // row 2j
            unsigned o1 = __builtin_amdgcn_readlane(cand, 32 + l1);   // row 2j+1
            acc |= ((unsigned long long)o0 << (16 * j)) |
                   ((unsigned long long)o1 << (16 * j + 8));
        }
        return acc;
    };
    auto put = [&](int st, int pt, unsigned long long v) {
        if (lane == st) myu[st * NPACK + pt] = v;
    };

    // ---- Phase A: PRE + K (rel 48..56) + L (rel 56..64), 4-slot distance-3 ----
    {
        int pa = base - 16, pb = base - 8;
        if (pa < 0) pa = 0;                // wq==0: garbage; chunk0 exact-init
        if (pb < 0) pb = 0;
        // group g=0..19 -> rows; g>=17 are Phase B preps e=g-17 (p=0,k=e)
        auto grows = [&](int gx, int& r0a, int& r0b) {
            if (gx == 0)       { r0a = pa; r0b = pb; }
            else if (gx <= 8)  { int i = gx - 1; r0a = base + (2 * i) * 64 + 48; r0b = base + (2 * i + 1) * 64 + 48; }
            else if (gx <= 16) { int i = gx - 9; r0a = base + (2 * i) * 64 + 56; r0b = base + (2 * i + 1) * 64 + 56; }
            else               { int e = gx - 17; r0a = base + (2 * e) * 64; r0b = r0a + 64; }
        };
        auto deposit = [&](int gi, unsigned long long a0, unsigned long long a1) {
            if (gi == 0) {                                   // PRE -> (0,p0),(0,p1)
                put(0, 0, a0); put(0, 1, a1);
            } else if (gi <= 8) {                            // K: (c,p8) & (c+1,p0)
                int i = gi - 1;
                put(2 * i, 8, a0);     put(2 * i + 1, 0, a0);
                put(2 * i + 1, 8, a1); if (2 * i + 2 <= 15) put(2 * i + 2, 0, a1);
            } else {                                         // L: (c,p9) & (c+1,p1)
                int i = gi - 9;
                put(2 * i, 9, a0);     put(2 * i + 1, 1, a0);
                put(2 * i + 1, 9, a1); if (2 * i + 2 <= 15) put(2 * i + 2, 1, a1);
            }
        };
        int ra, rb;
        grows(0, ra, rb); issue16(bA, ra, rb);
        grows(1, ra, rb); issue16(bB, ra, rb);
        grows(2, ra, rb); issue16(bC, ra, rb);
        for (int gb = 0; gb < 16; gb += 4) {                 // gi = gb+u, slot = u
            {   unsigned long long a0 = ext8(bA, 0), a1 = ext8(bA, 1);
                grows(gb + 3, ra, rb); issue16(bD, ra, rb);  // (gb+3)%4 = 3
                deposit(gb + 0, a0, a1); }
            {   unsigned long long a0 = ext8(bB, 0), a1 = ext8(bB, 1);
                grows(gb + 4, ra, rb); issue16(bA, ra, rb);  // %4 = 0
                deposit(gb + 1, a0, a1); }
            {   unsigned long long a0 = ext8(bC, 0), a1 = ext8(bC, 1);
                grows(gb + 5, ra, rb); issue16(bB, ra, rb);  // %4 = 1
                deposit(gb + 2, a0, a1); }
            {   unsigned long long a0 = ext8(bD, 0), a1 = ext8(bD, 1);
                grows(gb + 6, ra, rb); issue16(bC, ra, rb);  // %4 = 2
                deposit(gb + 3, a0, a1); }
        }
        {   // tail gi = 16 (slot 0); issues j=19 = prep e=2 -> slot 3 = sigma(2)
            unsigned long long a0 = ext8(bA, 0), a1 = ext8(bA, 1);
            grows(19, ra, rb); issue16(bD, ra, rb);
            deposit(16, a0, a1); }
        // preps e=0,1,2 were issued at gi=14,15,16 into slots 1,2,3 = sigma(e);
        // slot A is refilled in-loop at e=0 for e=3. No further prep needed.
    }

    // ---- Phase B: scan packs 0..9; packs 0..5 interleave extraction ----
    BFU Bf[2];
#pragma unroll
    for (int kf = 0; kf < 2; ++kf)
#pragma unroll
        for (int j = 0; j < 4; ++j) Bf[kf].u[j] = 0x3F803F80u;  // 1.0 burn seed

    float S0v = 0.f, swv = 1.f;

    for (int p = 0; p < NPACK; ++p) {
        unsigned long long uv = myu[s * NPACK + p];   // this pack's o-bytes
        const bool exsl = (p < 6);
#pragma unroll
        for (int k = 0; k < 8; ++k) {
            // --- MFMA section first (issue, don't consume yet) ---
            const int o = (int)(uv & 255ull);
            uv >>= 8;
            const float* br = &BmL[o * BMS];          // per-stream row, bank-phased
            f32x4 z0[4], z1[4];
#pragma unroll
            for (int mt = 0; mt < 4; ++mt) {
                f32x4 zr = {0.f, 0.f, 0.f, 0.f};
                z0[mt] = __builtin_amdgcn_mfma_f32_16x16x32_bf16(Af[mt][0].v, Bf[0].v, zr, 0, 0, 0);
                z1[mt] = __builtin_amdgcn_mfma_f32_16x16x32_bf16(Af[mt][1].v, Bf[1].v, zr, 0, 0, 0);
            }
            // --- extraction (vmcnt wait overlaps MFMAs); distance 3-4 refill ---
            if (exsl) {
                unsigned long long a0, a1;
                // slot sigma = (k+1)&3 : 1=B, 2=C, 3=D, 0=A (k compile-time)
                if (((k + 1) & 3) == 1)      { a0 = ext8(bB, 0); a1 = ext8(bB, 1); }
                else if (((k + 1) & 3) == 2) { a0 = ext8(bC, 0); a1 = ext8(bC, 1); }
                else if (((k + 1) & 3) == 3) { a0 = ext8(bD, 0); a1 = ext8(bD, 1); }
                else                         { a0 = ext8(bA, 0); a1 = ext8(bA, 1); }
                // refill pairs: k%4==0 -> A<-e+3, B<-e+4 ; k%4==2 -> C<-e+3, D<-e+4
                if ((k & 3) == 0) {
                    {   const int kt = k + 3;
                        const int k2 = (kt >= 8) ? kt - 8 : kt;
                        const int pd = (kt >= 8) ? 1 : 0;
                        int p2 = p + pd;
                        if (p2 < 6) { int r0 = base + (2 * k2) * 64 + 8 * p2; issue16(bA, r0, r0 + 64); } }
                    {   const int kt = k + 4;
                        const int k2 = (kt >= 8) ? kt - 8 : kt;
                        const int pd = (kt >= 8) ? 1 : 0;
                        int p2 = p + pd;
                        if (p2 < 6) { int r0 = base + (2 * k2) * 64 + 8 * p2; issue16(bB, r0, r0 + 64); } }
                } else if ((k & 3) == 2) {
                    {   const int kt = k + 3;
                        const int k2 = (kt >= 8) ? kt - 8 : kt;
                        const int pd = (kt >= 8) ? 1 : 0;
                        int p2 = p + pd;
                        if (p2 < 6) { int r0 = base + (2 * k2) * 64 + 8 * p2; issue16(bC, r0, r0 + 64); } }
                    {   const int kt = k + 4;
                        const int k2 = (kt >= 8) ? kt - 8 : kt;
                        const int pd = (kt >= 8) ? 1 : 0;
                        int p2 = p + pd;
                        if (p2 < 6) { int r0 = base + (2 * k2) * 64 + 8 * p2; issue16(bD, r0, r0 + 64); } }
                }
                put(2 * k, p + 2, a0);
                put(2 * k + 1, p + 2, a1);
            }
            // --- consume MFMA results (E read here: out of the peak window) ---
            float w[4][4];
#pragma unroll
            for (int mt = 0; mt < 4; ++mt) {
                f32x4 E = *(const f32x4*)&br[mt * 16 + g * 4];
#pragma unroll
                for (int r = 0; r < 4; ++r) w[mt][r] = (z0[mt][r] + z1[mt][r]) * E[r];
            }
            if (p == BURNP && k == 0 && wq == 0) {    // exact t=0 init of chunk 0
                const bool c0 = (s == 0);
#pragma unroll
                for (int mt = 0; mt < 4; ++mt)
#pragma unroll
                    for (int r = 0; r < 4; ++r)
                        w[mt][r] = c0 ? ILds[mt * 16 + g * 4 + r] * (*(const f32x4*)&br[mt * 16 + g * 4])[r] : w[mt][r];
            }
            if (k == 7 && (p == BURNP - 1 || p == NPACK - 1)) {  // mass (pre-scale)
                float swl = 0.f;
#pragma unroll
                for (int mt = 0; mt < 4; ++mt)
#pragma unroll
                    for (int r = 0; r < 4; ++r) swl += w[mt][r];
                swl += __shfl_xor(swl, 16);
                swl += __shfl_xor(swl, 32);
                swv = swl;
            }
            // zero-shuffle C->B under pi; constant 2^56 rescale at k==7
#pragma unroll
            for (int kf = 0; kf < 2; ++kf)
#pragma unroll
                for (int j2 = 0; j2 < 4; ++j2) {
                    int mt = 2 * kf + (j2 >> 1), pr = j2 & 1;
                    float v0 = w[mt][2 * pr], v1 = w[mt][2 * pr + 1];
                    if (k == 7) { v0 *= SCALEF; v1 *= SCALEF; }
                    Bf[kf].u[j2] = pk_trunc(v0, v1);
                }
        }
        if (p == BURNP - 1) {
            // exponents: burn mass carries 1*RB, final carries (NPACK-1)*RB
            const bool ch0 = (wq == 0) && (s == 0);
            S0v = ch0 ? ((float)(NPACK - 1 - BURNP) * RB)
                      : (__log2f(swv) + (float)(NPACK - BURNP) * RB);
        }
    }

    float tot = __log2f(swv) - S0v;
    // sum over the 16 streams (s-dim); g-lanes hold duplicates
    tot += __shfl_xor(tot, 1);
    tot += __shfl_xor(tot, 2);
    tot += __shfl_xor(tot, 4);
    tot += __shfl_xor(tot, 8);
    if (lane == 0)
        atomicAdd(out + seq, tot * 0.6931471805599453f);
}

extern "C" void kernel_launch(void* const* d_in, const int* in_sizes, int n_in,
                              void* d_out, int out_size, void* d_ws, size_t ws_size,
                              hipStream_t stream) {
    const float* x  = (const float*)d_in[0];   // [B,T,M] one-hot
    const float* I  = (const float*)d_in[1];   // [1,S]
    const float* A  = (const float*)d_in[2];   // [S,S]
    const float* Bm = (const float*)d_in[3];   // [M,S]
    float* out = (float*)d_out;                // [B,1]
    (void)d_ws; (void)ws_size;                 // workspace unused (fully fused)

    hipMemsetAsync(out, 0, (size_t)out_size * sizeof(float), stream);
    hmm_fused<<<(BATCH * 4) / WPB, WPB * 64, 0, stream>>>(x, I, A, Bm, out);  // 2048 waves
}

// Round 3
// 1334.641 us; speedup vs baseline: 1.0116x; 1.0116x over previous
//
#include <hip/hip_runtime.h>

// HMM forward (CgpHmmCell): B=512, T=4096, S=64, M=125.
// Round 20: SPLIT KERNELS via d_ws. Post-mortem R19: depth-4 in-register
// prefetch regressed (+54us) -- 128 VGPRs of buffers + ~130 VGPRs scan state
// crossed the 256 line under launch_bounds(256,2) -> spills. The register
// budget binds in-register prefetch depth; the fused kernel cannot be both a
// deep streamer and an MFMA scanner. But the scan only needs the o-byte
// index stream (1 B/row, 2 MB), not the 1.05 GB one-hot tensor. Split:
//   K1 hmm_extract: pure streamer. 4096 waves x 512 rows, 3-slot depth-3
//     rotation (96 buf VGPRs, ~125 total -> 4 waves/SIMD, 2x fused
//     occupancy). Identical ext8 (ballot) -> packed u64 o-bytes to d_ws.
//     No Phase A, no scan state, no per-step consume stalls.
//   K2 hmm_scan: R18 Phase B with extraction deleted. Each pack's 8 o-bytes
//     = one clamped u64 load from d_ws (L2/L3-resident), prefetched one pack
//     ahead. Phase A's 17 serial groups and all in-loop vmcnt waits vanish.
// Bit-exact vs R18: same ext8 bytes (incl. clamped wq==0 burn garbage rows
// 0..8 for packs 0,1), same o consumption order, same MFMA/rescale/mass/
// override arithmetic -> absmax 0.0. ws_size guard falls back to the exact
// R18 fused kernel. Workspace: 512*4096 = 2MB o-bytes.

#define BATCH 512
#define T 4096
#define S 64
#define M 125
#define BMS 68     // BmL row stride in dwords: 68%32=4 -> 8 bank phases, 16B-aligned
#define NPACK 10   // 2 burn + 8 accumulate (chunk = 64 steps)
#define BURNP 2
#define WPB 4
#define RB 56.0f
#define SCALEF 7.205759403792794e16f   // 2^56

typedef __attribute__((ext_vector_type(8))) short bf16x8;
typedef __attribute__((ext_vector_type(4))) float f32x4;
typedef float f32x4u __attribute__((ext_vector_type(4), aligned(4)));  // 4-B-aligned vec4

union BFU { unsigned u[4]; bf16x8 v; };

__device__ __forceinline__ unsigned pk_trunc(float a, float b) {
    return (__float_as_uint(b) & 0xFFFF0000u) | (__float_as_uint(a) >> 16);
}
__device__ __forceinline__ unsigned pk_rne(float a, float b) {
    unsigned ua = __float_as_uint(a); ua += 0x7FFFu + ((ua >> 16) & 1u);
    unsigned ub = __float_as_uint(b); ub += 0x7FFFu + ((ub >> 16) & 1u);
    return (ub & 0xFFFF0000u) | (ua >> 16);
}

// =====================  K1: o-byte extractor (BW-bound)  =====================
// 4096 waves, 512 rows each, 32 slot-steps of 16 rows, depth-3 A/B/C rotation.
__global__ __launch_bounds__(256) void hmm_extract(const float* __restrict__ x,
                                                   unsigned long long* __restrict__ ob) {
    const int tid = threadIdx.x, lane = tid & 63;
    const int W = blockIdx.x * WPB + (tid >> 6);          // 0..4095
    const int row0 = W * 512;                             // global first row
    const int rel = lane & 31, hf = lane >> 5;
    const unsigned coff = (rel < 31) ? 4u * (unsigned)rel : 121u;  // dword in row

    f32x4u bA[8], bB[8], bC[8];                           // three 16-row slots

    auto issue = [&](f32x4u (&bf)[8], int t) {
        const int r0 = row0 + 16 * t;
#pragma unroll
        for (int j = 0; j < 4; ++j) {
            unsigned ra = (unsigned)((r0 + 2 * j + hf) * 125) + coff;
            unsigned rb = (unsigned)((r0 + 8 + 2 * j + hf) * 125) + coff;
            bf[j]     = *(const f32x4u*)&x[ra];
            bf[4 + j] = *(const f32x4u*)&x[rb];
        }
    };
    auto ext8 = [&](const f32x4u (&bf)[8], int b) -> unsigned long long {
        unsigned long long acc = 0;
#pragma unroll
        for (int j = 0; j < 4; ++j) {
            f32x4u v = bf[b * 4 + j];
            bool nz = (v.x != 0.f) || (v.y != 0.f) || (v.z != 0.f) || (v.w != 0.f);
            unsigned li = (v.x != 0.f) ? 0u : ((v.y != 0.f) ? 1u : ((v.z != 0.f) ? 2u : 3u));
            unsigned cand = coff + li;
            unsigned long long m = __ballot(nz);          // one-hot => both halves nonzero
            unsigned l0 = (unsigned)__builtin_ctzll(m & 0xffffffffull);
            unsigned l1 = (unsigned)__builtin_ctzll(m >> 32);
            unsigned o0 = __builtin_amdgcn_readlane(cand, l0);        // row 2j
            unsigned o1 = __builtin_amdgcn_readlane(cand, 32 + l1);   // row 2j+1
            acc |= ((unsigned long long)o0 << (16 * j)) |
                   ((unsigned long long)o1 << (16 * j + 8));
        }
        return acc;
    };
    auto st = [&](int t, unsigned long long a0, unsigned long long a1) {
        if (lane == 0) {
            ob[(row0 >> 3) + 2 * t]     = a0;             // rows 16t..16t+8
            ob[(row0 >> 3) + 2 * t + 1] = a1;             // rows 16t+8..16t+16
        }
    };

    issue(bA, 0); issue(bB, 1); issue(bC, 2);
    for (int tb = 0; tb < 33; tb += 3) {
        {   const int t = tb;
            unsigned long long a0 = ext8(bA, 0), a1 = ext8(bA, 1);
            if (t + 3 < 32) issue(bA, t + 3);
            st(t, a0, a1); }
        if (tb + 1 < 32) { const int t = tb + 1;
            unsigned long long a0 = ext8(bB, 0), a1 = ext8(bB, 1);
            if (t + 3 < 32) issue(bB, t + 3);
            st(t, a0, a1); }
        if (tb + 2 < 32) { const int t = tb + 2;
            unsigned long long a0 = ext8(bC, 0), a1 = ext8(bC, 1);
            if (t + 3 < 32) issue(bC, t + 3);
            st(t, a0, a1); }
    }
}

// =====================  K2: MFMA scan (compute-bound)  =====================
// R18 Phase B; packs come as direct u64 loads from the o-byte workspace.
__global__ __launch_bounds__(256) void hmm_scan(const unsigned long long* __restrict__ ob,
                                                const float* __restrict__ Iv,
                                                const float* __restrict__ A,
                                                const float* __restrict__ Bm,
                                                float* __restrict__ out) {
    __shared__ __align__(16) float BmL[M * BMS];               // 34000 B
    __shared__ __align__(16) float ILds[S];

    const int tid = threadIdx.x, wv = tid >> 6, lane = tid & 63;
    const int s = lane & 15, g = lane >> 4;

    for (int i = tid; i < M * S; i += WPB * 64)
        BmL[(i >> 6) * BMS + (i & 63)] = Bm[i];
    if (tid < S) ILds[tid] = Iv[tid];
    __syncthreads();

    // A^T fragments under pi (identical to fused).
    BFU Af[4][2];
#pragma unroll
    for (int mt = 0; mt < 4; ++mt)
#pragma unroll
        for (int kf = 0; kf < 2; ++kf)
#pragma unroll
            for (int j2 = 0; j2 < 4; ++j2) {
                int p0 = 32 * kf + 16 * (j2 >> 1) + 4 * g + 2 * (j2 & 1);
                Af[mt][kf].u[j2] = pk_rne(A[(size_t)p0 * S + mt * 16 + s],
                                          A[(size_t)(p0 + 1) * S + mt * 16 + s]);
            }

    const int W = blockIdx.x * WPB + wv;   // 0..2047
    const int seq = W >> 2, wq = W & 3;
    const int base = wq * 1024;
    const unsigned long long* os = ob + (size_t)seq * (T / 8);   // 512 u64 / seq
    const int B0 = (base >> 3) + 8 * s;    // u64 index of stream s's chunk start
    // pack p wants u64 index B0 + p - 2 (p<2: previous-chunk burn rows; wq==0
    // s==0 clamps to 0 == fused kernel's pa/pb clamp -> identical garbage).

    BFU Bf[2];
#pragma unroll
    for (int kf = 0; kf < 2; ++kf)
#pragma unroll
        for (int j = 0; j < 4; ++j) Bf[kf].u[j] = 0x3F803F80u;  // 1.0 burn seed

    float S0v = 0.f, swv = 1.f;

    int i0 = B0 - 2; if (i0 < 0) i0 = 0;
    unsigned long long uvc = os[i0];       // pack 0

    for (int p = 0; p < NPACK; ++p) {
        unsigned long long uvn = 0;
        if (p + 1 < NPACK) {               // prefetch next pack (L2/L3-resident)
            int ix = B0 + (p + 1) - 2; if (ix < 0) ix = 0;
            uvn = os[ix];
        }
        unsigned long long uv = uvc;
#pragma unroll
        for (int k = 0; k < 8; ++k) {
            const int o = (int)(uv & 255ull);
            uv >>= 8;
            const float* br = &BmL[o * BMS];          // per-stream row, bank-phased
            f32x4 E[4], z0[4], z1[4];
#pragma unroll
            for (int mt = 0; mt < 4; ++mt) {
                E[mt] = *(const f32x4*)&br[mt * 16 + g * 4];
                f32x4 zr = {0.f, 0.f, 0.f, 0.f};
                z0[mt] = __builtin_amdgcn_mfma_f32_16x16x32_bf16(Af[mt][0].v, Bf[0].v, zr, 0, 0, 0);
                z1[mt] = __builtin_amdgcn_mfma_f32_16x16x32_bf16(Af[mt][1].v, Bf[1].v, zr, 0, 0, 0);
            }
            float w[4][4];
#pragma unroll
            for (int mt = 0; mt < 4; ++mt)
#pragma unroll
                for (int r = 0; r < 4; ++r) w[mt][r] = (z0[mt][r] + z1[mt][r]) * E[mt][r];
            if (p == BURNP && k == 0 && wq == 0) {    // exact t=0 init of chunk 0
                const bool c0 = (s == 0);
#pragma unroll
                for (int mt = 0; mt < 4; ++mt)
#pragma unroll
                    for (int r = 0; r < 4; ++r)
                        w[mt][r] = c0 ? ILds[mt * 16 + g * 4 + r] * E[mt][r] : w[mt][r];
            }
            if (k == 7 && (p == BURNP - 1 || p == NPACK - 1)) {  // mass (pre-scale)
                float swl = 0.f;
#pragma unroll
                for (int mt = 0; mt < 4; ++mt)
#pragma unroll
                    for (int r = 0; r < 4; ++r) swl += w[mt][r];
                swl += __shfl_xor(swl, 16);
                swl += __shfl_xor(swl, 32);
                swv = swl;
            }
            // zero-shuffle C->B under pi; constant 2^56 rescale at k==7
#pragma unroll
            for (int kf = 0; kf < 2; ++kf)
#pragma unroll
                for (int j2 = 0; j2 < 4; ++j2) {
                    int mt = 2 * kf + (j2 >> 1), pr = j2 & 1;
                    float v0 = w[mt][2 * pr], v1 = w[mt][2 * pr + 1];
                    if (k == 7) { v0 *= SCALEF; v1 *= SCALEF; }
                    Bf[kf].u[j2] = pk_trunc(v0, v1);
                }
        }
        uvc = uvn;
        if (p == BURNP - 1) {
            const bool ch0 = (wq == 0) && (s == 0);
            S0v = ch0 ? ((float)(NPACK - 1 - BURNP) * RB)
                      : (__log2f(swv) + (float)(NPACK - BURNP) * RB);
        }
    }

    float tot = __log2f(swv) - S0v;
    tot += __shfl_xor(tot, 1);
    tot += __shfl_xor(tot, 2);
    tot += __shfl_xor(tot, 4);
    tot += __shfl_xor(tot, 8);
    if (lane == 0)
        atomicAdd(out + seq, tot * 0.6931471805599453f);
}

// ============  Fallback: R18 fused kernel (exact copy, ws-free)  ============
__global__ __launch_bounds__(256) void hmm_fused(const float* __restrict__ x,
                                                 const float* __restrict__ Iv,
                                                 const float* __restrict__ A,
                                                 const float* __restrict__ Bm,
                                                 float* __restrict__ out) {
    __shared__ __align__(16) float BmL[M * BMS];
    __shared__ __align__(16) float ILds[S];
    __shared__ unsigned long long ulds[WPB * 16 * NPACK];

    const int tid = threadIdx.x, wv = tid >> 6, lane = tid & 63;
    const int s = lane & 15, g = lane >> 4;

    for (int i = tid; i < M * S; i += WPB * 64)
        BmL[(i >> 6) * BMS + (i & 63)] = Bm[i];
    if (tid < S) ILds[tid] = Iv[tid];
    __syncthreads();

    BFU Af[4][2];
#pragma unroll
    for (int mt = 0; mt < 4; ++mt)
#pragma unroll
        for (int kf = 0; kf < 2; ++kf)
#pragma unroll
            for (int j2 = 0; j2 < 4; ++j2) {
                int p0 = 32 * kf + 16 * (j2 >> 1) + 4 * g + 2 * (j2 & 1);
                Af[mt][kf].u[j2] = pk_rne(A[(size_t)p0 * S + mt * 16 + s],
                                          A[(size_t)(p0 + 1) * S + mt * 16 + s]);
            }

    const int W = blockIdx.x * WPB + wv;
    const int seq = W >> 2, wq = W & 3;
    const float* xs = x + (size_t)seq * T * M;
    unsigned long long* myu = &ulds[wv * 16 * NPACK];
    const int base = wq * 1024;

    const int rel = lane & 31, hf = lane >> 5;
    const unsigned coff = (rel < 31) ? 4u * (unsigned)rel : 121u;

    f32x4u bufP[8], bufQ[8];

    auto issue16 = [&](f32x4u (&bf)[8], int r0a, int r0b) {
#pragma unroll
        for (int j = 0; j < 4; ++j) {
            unsigned ra = (unsigned)((r0a + 2 * j + hf) * 125) + coff;
            unsigned rb = (unsigned)((r0b + 2 * j + hf) * 125) + coff;
            bf[j]     = *(const f32x4u*)&xs[ra];
            bf[4 + j] = *(const f32x4u*)&xs[rb];
        }
    };
    auto ext8 = [&](const f32x4u (&bf)[8], int b) -> unsigned long long {
        unsigned long long acc = 0;
#pragma unroll
        for (int j = 0; j < 4; ++j) {
            f32x4u v = bf[b * 4 + j];
            bool nz = (v.x != 0.f) || (v.y != 0.f) || (v.z != 0.f) || (v.w != 0.f);
            unsigned li = (v.x != 0.f) ? 0u : ((v.y != 0.f) ? 1u : ((v.z != 0.f) ? 2u : 3u));
            unsigned cand = coff + li;
            unsigned long long m = __ballot(nz);
            unsigned l0 = (unsigned)__builtin_ctzll(m & 0xffffffffull);
            unsigned l1 = (unsigned)__builtin_ctzll(m >> 32);
            unsigned o0 = __builtin_amdgcn_readlane(cand, l0);
            unsigned o1 = __builtin_amdgcn_readlane(cand, 32 + l1);
            acc |= ((unsigned long long)o0 << (16 * j)) |
                   ((unsigned long long)o1 << (16 * j + 8));
        }
        return acc;
    };
    auto put = [&](int st, int pt, unsigned long long v) {
        if (lane == st) myu[st * NPACK + pt] = v;
    };

    {
        int pa = base - 16, pb = base - 8;
        if (pa < 0) pa = 0;
        if (pb < 0) pb = 0;
        issue16(bufP, pa, pb);
        for (int gi = 0; gi <= 16; ++gi) {
            unsigned long long a0 = ext8(bufP, 0), a1 = ext8(bufP, 1);
            if (gi < 16) {
                int ni = gi + 1;
                if (ni <= 8) { int i = ni - 1; issue16(bufP, base + (2 * i) * 64 + 48, base + (2 * i + 1) * 64 + 48); }
                else         { int i = ni - 9; issue16(bufP, base + (2 * i) * 64 + 56, base + (2 * i + 1) * 64 + 56); }
            } else {
                issue16(bufP, base + 0, base + 64);
            }
            if (gi == 0) {
                put(0, 0, a0); put(0, 1, a1);
            } else if (gi <= 8) {
                int i = gi - 1;
                put(2 * i, 8, a0);     put(2 * i + 1, 0, a0);
                put(2 * i + 1, 8, a1); if (2 * i + 2 <= 15) put(2 * i + 2, 0, a1);
            } else {
                int i = gi - 9;
                put(2 * i, 9, a0);     put(2 * i + 1, 1, a0);
                put(2 * i + 1, 9, a1); if (2 * i + 2 <= 15) put(2 * i + 2, 1, a1);
            }
        }
        issue16(bufQ, base + 128, base + 192);
    }

    BFU Bf[2];
#pragma unroll
    for (int kf = 0; kf < 2; ++kf)
#pragma unroll
        for (int j = 0; j < 4; ++j) Bf[kf].u[j] = 0x3F803F80u;

    float S0v = 0.f, swv = 1.f;

    for (int p = 0; p < NPACK; ++p) {
        unsigned long long uv = myu[s * NPACK + p];
        const bool exsl = (p < 6);
#pragma unroll
        for (int k = 0; k < 8; ++k) {
            const int o = (int)(uv & 255ull);
            uv >>= 8;
            const float* br = &BmL[o * BMS];
            f32x4 E[4], z0[4], z1[4];
#pragma unroll
            for (int mt = 0; mt < 4; ++mt) {
                E[mt] = *(const f32x4*)&br[mt * 16 + g * 4];
                f32x4 zr = {0.f, 0.f, 0.f, 0.f};
                z0[mt] = __builtin_amdgcn_mfma_f32_16x16x32_bf16(Af[mt][0].v, Bf[0].v, zr, 0, 0, 0);
                z1[mt] = __builtin_amdgcn_mfma_f32_16x16x32_bf16(Af[mt][1].v, Bf[1].v, zr, 0, 0, 0);
            }
            if (exsl) {
                unsigned long long a0, a1;
                if ((k & 1) == 0) { a0 = ext8(bufP, 0); a1 = ext8(bufP, 1); }
                else              { a0 = ext8(bufQ, 0); a1 = ext8(bufQ, 1); }
                int k2 = k + 2, p2 = p;
                bool ok = true;
                if (k2 >= 8) { k2 -= 8; p2 = p + 1; ok = (p2 < 6); }
                if (ok) {
                    int r0a = base + (2 * k2) * 64 + 8 * p2;
                    if ((k & 1) == 0) issue16(bufP, r0a, r0a + 64);
                    else              issue16(bufQ, r0a, r0a + 64);
                }
                put(2 * k, p + 2, a0);
                put(2 * k + 1, p + 2, a1);
            }
            float w[4][4];
#pragma unroll
            for (int mt = 0; mt < 4; ++mt)
#pragma unroll
                for (int r = 0; r < 4; ++r) w[mt][r] = (z0[mt][r] + z1[mt][r]) * E[mt][r];
            if (p == BURNP && k == 0 && wq == 0) {
                const bool c0 = (s == 0);
#pragma unroll
                for (int mt = 0; mt < 4; ++mt)
#pragma unroll
                    for (int r = 0; r < 4; ++r)
                        w[mt][r] = c0 ? ILds[mt * 16 + g * 4 + r] * E[mt][r] : w[mt][r];
            }
            if (k == 7 && (p == BURNP - 1 || p == NPACK - 1)) {
                float swl = 0.f;
#pragma unroll
                for (int mt = 0; mt < 4; ++mt)
#pragma unroll
                    for (int r = 0; r < 4; ++r) swl += w[mt][r];
                swl += __shfl_xor(swl, 16);
                swl += __shfl_xor(swl, 32);
                swv = swl;
            }
#pragma unroll
            for (int kf = 0; kf < 2; ++kf)
#pragma unroll
                for (int j2 = 0; j2 < 4; ++j2) {
                    int mt = 2 * kf + (j2 >> 1), pr = j2 & 1;
                    float v0 = w[mt][2 * pr], v1 = w[mt][2 * pr + 1];
                    if (k == 7) { v0 *= SCALEF; v1 *= SCALEF; }
                    Bf[kf].u[j2] = pk_trunc(v0, v1);
                }
        }
        if (p == BURNP - 1) {
            const bool ch0 = (wq == 0) && (s == 0);
            S0v = ch0 ? ((float)(NPACK - 1 - BURNP) * RB)
                      : (__log2f(swv) + (float)(NPACK - BURNP) * RB);
        }
    }

    float tot = __log2f(swv) - S0v;
    tot += __shfl_xor(tot, 1);
    tot += __shfl_xor(tot, 2);
    tot += __shfl_xor(tot, 4);
    tot += __shfl_xor(tot, 8);
    if (lane == 0)
        atomicAdd(out + seq, tot * 0.6931471805599453f);
}

extern "C" void kernel_launch(void* const* d_in, const int* in_sizes, int n_in,
                              void* d_out, int out_size, void* d_ws, size_t ws_size,
                              hipStream_t stream) {
    const float* x  = (const float*)d_in[0];   // [B,T,M] one-hot
    const float* I  = (const float*)d_in[1];   // [1,S]
    const float* A  = (const float*)d_in[2];   // [S,S]
    const float* Bm = (const float*)d_in[3];   // [M,S]
    float* out = (float*)d_out;                // [B,1]

    hipMemsetAsync(out, 0, (size_t)out_size * sizeof(float), stream);

    const size_t need = (size_t)BATCH * T;     // 2 MB of o-bytes
    if (d_ws != nullptr && ws_size >= need) {
        unsigned long long* ob = (unsigned long long*)d_ws;
        hmm_extract<<<(BATCH * T / 512) / WPB, WPB * 64, 0, stream>>>(x, ob);       // 4096 waves
        hmm_scan<<<(BATCH * 4) / WPB, WPB * 64, 0, stream>>>(ob, I, A, Bm, out);    // 2048 waves
    } else {
        hmm_fused<<<(BATCH * 4) / WPB, WPB * 64, 0, stream>>>(x, I, A, Bm, out);    // 2048 waves
    }
}

// Round 4
// 1323.343 us; speedup vs baseline: 1.0202x; 1.0085x over previous
//
#include <hip/hip_runtime.h>

// HMM forward (CgpHmmCell): B=512, T=4096, S=64, M=125.
// Round 21: TEMPORAL PHASE SPLIT in one kernel. Post-mortems: R19 depth-4
// in-register prefetch spilled (buffers + scan state concurrently live >256
// VGPR); R20 two-kernel split removed the register conflict but serialized
// extract->scan across the whole grid (+38us vs fused). Key fact: each wave
// scans exactly the o-bytes it extracts (private 1.28KB ulds slice). So:
// Phase 1 (per wave): PURE streamer -- no scan state live -> depth-4 slot
//   rotation bufA..D (128 VGPRs, compile-time indexed), 65 uniform 16-row
//   groups (rows base-16..base+1023), ballot-ext -> LDS deposits. The old
//   Phase-A dist-1 serialization (~17 latency-bound groups) is gone.
// Phase 2 (per wave): PURE scan -- buffers dead, registers reallocate to
//   Af/Bf/z/E/w. 80 MFMA iterations fed from ulds, zero global loads.
// Bit-exact vs R18/R20 (absmax 0.0): each u64 is built from one 8-row group
// independently, so linear regrouping of the fused slot order yields
// identical myu contents. Group 0 replicates the fused pa/pb clamp (wq==0
// reads rows 0..7 twice). Deposit map: group i>=1 covers q=2(i-1),2(i-1)+1
// (8-row units from base); q -> put(q>>3, (q&7)+2) plus dual-deposit
// put(s+1, pos-6) for pos>=6, s<15. 2+128+30 = 160 slots filled once each.
// Phase 2 = R20's K2 body (verified absmax 0.0) reading LDS. d_ws unused.

#define BATCH 512
#define T 4096
#define S 64
#define M 125
#define BMS 68     // BmL row stride in dwords: 68%32=4 -> 8 bank phases, 16B-aligned
#define NPACK 10   // 2 burn + 8 accumulate (chunk = 64 steps)
#define BURNP 2
#define WPB 4
#define RB 56.0f
#define SCALEF 7.205759403792794e16f   // 2^56

typedef __attribute__((ext_vector_type(8))) short bf16x8;
typedef __attribute__((ext_vector_type(4))) float f32x4;
typedef float f32x4u __attribute__((ext_vector_type(4), aligned(4)));  // 4-B-aligned vec4

union BFU { unsigned u[4]; bf16x8 v; };

__device__ __forceinline__ unsigned pk_trunc(float a, float b) {
    return (__float_as_uint(b) & 0xFFFF0000u) | (__float_as_uint(a) >> 16);
}
__device__ __forceinline__ unsigned pk_rne(float a, float b) {
    unsigned ua = __float_as_uint(a); ua += 0x7FFFu + ((ua >> 16) & 1u);
    unsigned ub = __float_as_uint(b); ub += 0x7FFFu + ((ub >> 16) & 1u);
    return (ub & 0xFFFF0000u) | (ua >> 16);
}

__global__ __launch_bounds__(256) void hmm_fused(const float* __restrict__ x,
                                                 const float* __restrict__ Iv,
                                                 const float* __restrict__ A,
                                                 const float* __restrict__ Bm,
                                                 float* __restrict__ out) {
    __shared__ __align__(16) float BmL[M * BMS];               // 34000 B
    __shared__ __align__(16) float ILds[S];
    __shared__ unsigned long long ulds[WPB * 16 * NPACK];      // 5120 B

    const int tid = threadIdx.x, wv = tid >> 6, lane = tid & 63;
    const int s = lane & 15, g = lane >> 4;

    for (int i = tid; i < M * S; i += WPB * 64)
        BmL[(i >> 6) * BMS + (i & 63)] = Bm[i];
    if (tid < S) ILds[tid] = Iv[tid];
    __syncthreads();

    const int W = blockIdx.x * WPB + wv;   // 0..2047
    const int seq = W >> 2, wq = W & 3;    // 4 waves per sequence
    const float* xs = x + (size_t)seq * T * M;
    unsigned long long* myu = &ulds[wv * 16 * NPACK];
    const int base = wq * 1024;            // wave's first row (seq-relative)

    const int rel = lane & 31, hf = lane >> 5;
    const unsigned coff = (rel < 31) ? 4u * (unsigned)rel : 121u;  // dword in row

    // =================== Phase 1: pure extraction streamer ===================
    {
        f32x4u bA[8], bB[8], bC[8], bD[8];     // depth-4 rotation, 128 VGPRs

        auto issue16 = [&](f32x4u (&bf)[8], int r0a, int r0b) {
#pragma unroll
            for (int j = 0; j < 4; ++j) {
                unsigned ra = (unsigned)((r0a + 2 * j + hf) * 125) + coff;
                unsigned rb = (unsigned)((r0b + 2 * j + hf) * 125) + coff;
                bf[j]     = *(const f32x4u*)&xs[ra];
                bf[4 + j] = *(const f32x4u*)&xs[rb];
            }
        };
        auto ext8 = [&](const f32x4u (&bf)[8], int b) -> unsigned long long {
            unsigned long long acc = 0;
#pragma unroll
            for (int j = 0; j < 4; ++j) {
                f32x4u v = bf[b * 4 + j];
                bool nz = (v.x != 0.f) || (v.y != 0.f) || (v.z != 0.f) || (v.w != 0.f);
                unsigned li = (v.x != 0.f) ? 0u : ((v.y != 0.f) ? 1u : ((v.z != 0.f) ? 2u : 3u));
                unsigned cand = coff + li;                 // dword index of first nz
                unsigned long long m = __ballot(nz);       // one-hot => both halves nonzero
                unsigned l0 = (unsigned)__builtin_ctzll(m & 0xffffffffull);
                unsigned l1 = (unsigned)__builtin_ctzll(m >> 32);
                unsigned o0 = __builtin_amdgcn_readlane(cand, l0);        // row 2j
                unsigned o1 = __builtin_amdgcn_readlane(cand, 32 + l1);   // row 2j+1
                acc |= ((unsigned long long)o0 << (16 * j)) |
                       ((unsigned long long)o1 << (16 * j + 8));
            }
            return acc;
        };
        auto put = [&](int st, int pt, unsigned long long v) {
            if (lane == st) myu[st * NPACK + pt] = v;
        };
        // group i (0..64) -> two source row-halves
        auto grows = [&](int i, int& r0a, int& r0b) {
            if (i == 0) {
                r0a = base - 16; if (r0a < 0) r0a = 0;     // fused pa clamp
                r0b = base - 8;  if (r0b < 0) r0b = 0;     // fused pb clamp
            } else {
                r0a = base + 16 * (i - 1);
                r0b = r0a + 8;
            }
        };
        auto depq = [&](int q, unsigned long long a) {     // q = 8-row unit from base
            int sc = q >> 3, pos = q & 7;
            put(sc, pos + 2, a);
            if (pos >= 6 && sc < 15) put(sc + 1, pos - 6, a);
        };
        auto dep = [&](int i, unsigned long long a0, unsigned long long a1) {
            if (i == 0) { put(0, 0, a0); put(0, 1, a1); }  // burn rows
            else        { depq(2 * (i - 1), a0); depq(2 * (i - 1) + 1, a1); }
        };

        int ra, rb;
        grows(0, ra, rb); issue16(bA, ra, rb);
        grows(1, ra, rb); issue16(bB, ra, rb);
        grows(2, ra, rb); issue16(bC, ra, rb);
        grows(3, ra, rb); issue16(bD, ra, rb);
        for (int ib = 0; ib < 64; ib += 4) {               // groups ib..ib+3
            {   unsigned long long a0 = ext8(bA, 0), a1 = ext8(bA, 1);
                if (ib + 4 <= 64) { grows(ib + 4, ra, rb); issue16(bA, ra, rb); }
                dep(ib + 0, a0, a1); }
            {   unsigned long long a0 = ext8(bB, 0), a1 = ext8(bB, 1);
                if (ib + 5 <= 64) { grows(ib + 5, ra, rb); issue16(bB, ra, rb); }
                dep(ib + 1, a0, a1); }
            {   unsigned long long a0 = ext8(bC, 0), a1 = ext8(bC, 1);
                if (ib + 6 <= 64) { grows(ib + 6, ra, rb); issue16(bC, ra, rb); }
                dep(ib + 2, a0, a1); }
            {   unsigned long long a0 = ext8(bD, 0), a1 = ext8(bD, 1);
                if (ib + 7 <= 64) { grows(ib + 7, ra, rb); issue16(bD, ra, rb); }
                dep(ib + 3, a0, a1); }
        }
        {   // tail group 64 (64&3 == 0 -> slot A)
            unsigned long long a0 = ext8(bA, 0), a1 = ext8(bA, 1);
            dep(64, a0, a1); }
    }

    // ======================= Phase 2: pure MFMA scan =======================
    // A^T fragments under pi: slot (kf,g,j2,e) holds A[p0+e][16mt+s],
    // p0 = 32kf + 16*(j2>>1) + 4g + 2*(j2&1).
    BFU Af[4][2];
#pragma unroll
    for (int mt = 0; mt < 4; ++mt)
#pragma unroll
        for (int kf = 0; kf < 2; ++kf)
#pragma unroll
            for (int j2 = 0; j2 < 4; ++j2) {
                int p0 = 32 * kf + 16 * (j2 >> 1) + 4 * g + 2 * (j2 & 1);
                Af[mt][kf].u[j2] = pk_rne(A[(size_t)p0 * S + mt * 16 + s],
                                          A[(size_t)(p0 + 1) * S + mt * 16 + s]);
            }

    BFU Bf[2];
#pragma unroll
    for (int kf = 0; kf < 2; ++kf)
#pragma unroll
        for (int j = 0; j < 4; ++j) Bf[kf].u[j] = 0x3F803F80u;  // 1.0 burn seed

    float S0v = 0.f, swv = 1.f;

    for (int p = 0; p < NPACK; ++p) {
        unsigned long long uv = myu[s * NPACK + p];   // this pack's o-bytes
#pragma unroll
        for (int k = 0; k < 8; ++k) {
            const int o = (int)(uv & 255ull);
            uv >>= 8;
            const float* br = &BmL[o * BMS];          // per-stream row, bank-phased
            f32x4 E[4], z0[4], z1[4];
#pragma unroll
            for (int mt = 0; mt < 4; ++mt) {
                E[mt] = *(const f32x4*)&br[mt * 16 + g * 4];
                f32x4 zr = {0.f, 0.f, 0.f, 0.f};
                z0[mt] = __builtin_amdgcn_mfma_f32_16x16x32_bf16(Af[mt][0].v, Bf[0].v, zr, 0, 0, 0);
                z1[mt] = __builtin_amdgcn_mfma_f32_16x16x32_bf16(Af[mt][1].v, Bf[1].v, zr, 0, 0, 0);
            }
            float w[4][4];
#pragma unroll
            for (int mt = 0; mt < 4; ++mt)
#pragma unroll
                for (int r = 0; r < 4; ++r) w[mt][r] = (z0[mt][r] + z1[mt][r]) * E[mt][r];
            if (p == BURNP && k == 0 && wq == 0) {    // exact t=0 init of chunk 0
                const bool c0 = (s == 0);
#pragma unroll
                for (int mt = 0; mt < 4; ++mt)
#pragma unroll
                    for (int r = 0; r < 4; ++r)
                        w[mt][r] = c0 ? ILds[mt * 16 + g * 4 + r] * E[mt][r] : w[mt][r];
            }
            if (k == 7 && (p == BURNP - 1 || p == NPACK - 1)) {  // mass (pre-scale)
                float swl = 0.f;
#pragma unroll
                for (int mt = 0; mt < 4; ++mt)
#pragma unroll
                    for (int r = 0; r < 4; ++r) swl += w[mt][r];
                swl += __shfl_xor(swl, 16);
                swl += __shfl_xor(swl, 32);
                swv = swl;
            }
            // zero-shuffle C->B under pi; constant 2^56 rescale at k==7
#pragma unroll
            for (int kf = 0; kf < 2; ++kf)
#pragma unroll
                for (int j2 = 0; j2 < 4; ++j2) {
                    int mt = 2 * kf + (j2 >> 1), pr = j2 & 1;
                    float v0 = w[mt][2 * pr], v1 = w[mt][2 * pr + 1];
                    if (k == 7) { v0 *= SCALEF; v1 *= SCALEF; }
                    Bf[kf].u[j2] = pk_trunc(v0, v1);
                }
        }
        if (p == BURNP - 1) {
            // exponents: burn mass carries 1*RB, final carries (NPACK-1)*RB
            const bool ch0 = (wq == 0) && (s == 0);
            S0v = ch0 ? ((float)(NPACK - 1 - BURNP) * RB)
                      : (__log2f(swv) + (float)(NPACK - BURNP) * RB);
        }
    }

    float tot = __log2f(swv) - S0v;
    // sum over the 16 streams (s-dim); g-lanes hold duplicates
    tot += __shfl_xor(tot, 1);
    tot += __shfl_xor(tot, 2);
    tot += __shfl_xor(tot, 4);
    tot += __shfl_xor(tot, 8);
    if (lane == 0)
        atomicAdd(out + seq, tot * 0.6931471805599453f);
}

extern "C" void kernel_launch(void* const* d_in, const int* in_sizes, int n_in,
                              void* d_out, int out_size, void* d_ws, size_t ws_size,
                              hipStream_t stream) {
    const float* x  = (const float*)d_in[0];   // [B,T,M] one-hot
    const float* I  = (const float*)d_in[1];   // [1,S]
    const float* A  = (const float*)d_in[2];   // [S,S]
    const float* Bm = (const float*)d_in[3];   // [M,S]
    float* out = (float*)d_out;                // [B,1]
    (void)d_ws; (void)ws_size;                 // workspace unused

    hipMemsetAsync(out, 0, (size_t)out_size * sizeof(float), stream);
    hmm_fused<<<(BATCH * 4) / WPB, WPB * 64, 0, stream>>>(x, I, A, Bm, out);  // 2048 waves
}

// Round 5
// 1303.510 us; speedup vs baseline: 1.0358x; 1.0152x over previous
//
#include <hip/hip_runtime.h>

// HMM forward (CgpHmmCell): B=512, T=4096, S=64, M=125.
// Round 22: PRODUCER/CONSUMER WAVE SPECIALIZATION. Post-mortems: extraction
// alone = 190us (89% BW), scan alone = ~95us (no HBM), and every same-wave
// organization (interleaved R18 = 275, split R20 = 313, phased R21 = 300)
// pays ~the serial sum -- R21 proved phases lockstep grid-wide. Overlap
// requires DIFFERENT waves: per block (256 thr), wv0,1 = producers (pure
// depth-3 streamers, no scan state), wv2,3 = consumers (pure scanners, no
// stream buffers). Producer j extracts quarter 2h+j (h=blockIdx&1) in R18
// Phase-A order: boundary g0, K g1-8 (pack 8 + pack-0 duals), L g9-16
// (pack 9 + pack-1 duals), then packs 2..7 stripe-strided (g17-64, 8 groups
// each); deposits u64 o-bytes into consumer's ulds slice; per-pack LDS flag
// set after s_waitcnt lgkmcnt(0). Flags 0,8 @g8; 1,9 @g16; p @g=24+8(p-2).
// Consumer spins (volatile LDS + s_sleep) on flag p, scans pack p while
// producer streams pack p+2. NO __syncthreads in loop -> producer vmcnt
// prefetch never drains across sync. launch_bounds(256,4) caps VGPR at 128
// (both paths ~116-120) -> 4 blocks/CU -> 1024-block grid fully co-resident.
// Bit-exact vs R18 (absmax 0.0): deposit map group-for-group identical (same
// clamps/duals; 2+31+31+96 = 160 slots once each); consumer = R20's verified
// K2 body. d_ws unused.

#define BATCH 512
#define T 4096
#define S 64
#define M 125
#define BMS 68     // BmL row stride in dwords: 68%32=4 -> 8 bank phases, 16B-aligned
#define NPACK 10   // 2 burn + 8 accumulate (chunk = 64 steps)
#define BURNP 2
#define RB 56.0f
#define SCALEF 7.205759403792794e16f   // 2^56

typedef __attribute__((ext_vector_type(8))) short bf16x8;
typedef __attribute__((ext_vector_type(4))) float f32x4;
typedef float f32x4u __attribute__((ext_vector_type(4), aligned(4)));  // 4-B-aligned vec4

union BFU { unsigned u[4]; bf16x8 v; };

__device__ __forceinline__ unsigned pk_trunc(float a, float b) {
    return (__float_as_uint(b) & 0xFFFF0000u) | (__float_as_uint(a) >> 16);
}
__device__ __forceinline__ unsigned pk_rne(float a, float b) {
    unsigned ua = __float_as_uint(a); ua += 0x7FFFu + ((ua >> 16) & 1u);
    unsigned ub = __float_as_uint(b); ub += 0x7FFFu + ((ub >> 16) & 1u);
    return (ub & 0xFFFF0000u) | (ua >> 16);
}

__global__ __launch_bounds__(256, 4) void hmm_fused(const float* __restrict__ x,
                                                    const float* __restrict__ Iv,
                                                    const float* __restrict__ A,
                                                    const float* __restrict__ Bm,
                                                    float* __restrict__ out) {
    __shared__ __align__(16) float BmL[M * BMS];               // 34000 B
    __shared__ __align__(16) float ILds[S];
    __shared__ unsigned long long ulds[2 * 16 * NPACK];        // 2560 B
    __shared__ unsigned fl[2 * NPACK];                         // pack-ready flags

    const int tid = threadIdx.x, wv = tid >> 6, lane = tid & 63;
    const int s = lane & 15, g = lane >> 4;

    for (int i = tid; i < M * S; i += 256)
        BmL[(i >> 6) * BMS + (i & 63)] = Bm[i];
    if (tid < S) ILds[tid] = Iv[tid];
    if (tid < 2 * NPACK) fl[tid] = 0u;
    __syncthreads();

    const int h = blockIdx.x & 1, seq = blockIdx.x >> 1;
    const int j = wv & 1;                  // producer/consumer pair index
    const int wq = 2 * h + j;              // quarter handled by this pair
    const int base = wq * 1024;            // quarter's first row (seq-relative)
    const float* xs = x + (size_t)seq * T * M;
    unsigned long long* myu = &ulds[j * 16 * NPACK];

    const int rel = lane & 31, hf = lane >> 5;
    const unsigned coff = (rel < 31) ? 4u * (unsigned)rel : 121u;  // dword in row

    if (wv < 2) {
        // ========================== PRODUCER ==========================
        f32x4u bA[8], bB[8], bC[8];        // depth-3 rotation, 96 VGPRs

        auto issue16 = [&](f32x4u (&bf)[8], int r0a, int r0b) {
#pragma unroll
            for (int jj = 0; jj < 4; ++jj) {
                unsigned ra = (unsigned)((r0a + 2 * jj + hf) * 125) + coff;
                unsigned rb = (unsigned)((r0b + 2 * jj + hf) * 125) + coff;
                bf[jj]     = *(const f32x4u*)&xs[ra];
                bf[4 + jj] = *(const f32x4u*)&xs[rb];
            }
        };
        auto ext8 = [&](const f32x4u (&bf)[8], int b) -> unsigned long long {
            unsigned long long acc = 0;
#pragma unroll
            for (int jj = 0; jj < 4; ++jj) {
                f32x4u v = bf[b * 4 + jj];
                bool nz = (v.x != 0.f) || (v.y != 0.f) || (v.z != 0.f) || (v.w != 0.f);
                unsigned li = (v.x != 0.f) ? 0u : ((v.y != 0.f) ? 1u : ((v.z != 0.f) ? 2u : 3u));
                unsigned cand = coff + li;                 // dword index of first nz
                unsigned long long m = __ballot(nz);       // one-hot => both halves nonzero
                unsigned l0 = (unsigned)__builtin_ctzll(m & 0xffffffffull);
                unsigned l1 = (unsigned)__builtin_ctzll(m >> 32);
                unsigned o0 = __builtin_amdgcn_readlane(cand, l0);        // row 2jj
                unsigned o1 = __builtin_amdgcn_readlane(cand, 32 + l1);   // row 2jj+1
                acc |= ((unsigned long long)o0 << (16 * jj)) |
                       ((unsigned long long)o1 << (16 * jj + 8));
            }
            return acc;
        };
        auto put = [&](int st, int pt, unsigned long long v) {
            if (lane == st) myu[st * NPACK + pt] = v;
        };
        // group gx (0..64) -> two 8-row source halves
        auto grows = [&](int gx, int& r0a, int& r0b) {
            if (gx == 0) {
                r0a = base - 16; if (r0a < 0) r0a = 0;     // R18 pa clamp
                r0b = base - 8;  if (r0b < 0) r0b = 0;     // R18 pb clamp
            } else if (gx <= 8) {          // K: pack 8 units, streams 2i,2i+1
                int i = gx - 1; r0a = base + 128 * i + 48; r0b = base + 128 * i + 112;
            } else if (gx <= 16) {         // L: pack 9 units
                int i = gx - 9; r0a = base + 128 * i + 56; r0b = base + 128 * i + 120;
            } else {                       // packs 2..7, streams si,si+1
                int b = gx - 17; int pb2 = b >> 3, si = 2 * (b & 7);
                r0a = base + 64 * si + 8 * pb2; r0b = r0a + 64;
            }
        };
        auto dep = [&](int gx, unsigned long long a0, unsigned long long a1) {
            if (gx == 0) { put(0, 0, a0); put(0, 1, a1); }
            else if (gx <= 8) { int i = gx - 1;              // K: (c,p8) & (c+1,p0)
                put(2 * i, 8, a0);     put(2 * i + 1, 0, a0);
                put(2 * i + 1, 8, a1); if (2 * i + 2 < 16) put(2 * i + 2, 0, a1);
            } else if (gx <= 16) { int i = gx - 9;           // L: (c,p9) & (c+1,p1)
                put(2 * i, 9, a0);     put(2 * i + 1, 1, a0);
                put(2 * i + 1, 9, a1); if (2 * i + 2 < 16) put(2 * i + 2, 1, a1);
            } else { int b = gx - 17; int p = (b >> 3) + 2, si = 2 * (b & 7);
                put(si, p, a0); put(si + 1, p, a1);
            }
        };
        auto flg = [&](int gx) {
            int f0 = -1, f1 = -1;
            if (gx == 8)       { f0 = 0; f1 = 8; }
            else if (gx == 16) { f0 = 1; f1 = 9; }
            else if (gx >= 24 && (gx & 7) == 0) f0 = 2 + ((gx - 24) >> 3);
            if (f0 >= 0) {
                asm volatile("s_waitcnt lgkmcnt(0)" ::: "memory");  // deposits visible
                if (lane == 0) {
                    *(volatile unsigned*)&fl[j * NPACK + f0] = 1u;
                    if (f1 >= 0) *(volatile unsigned*)&fl[j * NPACK + f1] = 1u;
                }
            }
        };

        int ra, rb;
        grows(0, ra, rb); issue16(bA, ra, rb);
        grows(1, ra, rb); issue16(bB, ra, rb);
        grows(2, ra, rb); issue16(bC, ra, rb);
        for (int gb = 0; gb < 65; gb += 3) {
            {   const int gx = gb;
                unsigned long long a0 = ext8(bA, 0), a1 = ext8(bA, 1);
                if (gx + 3 <= 64) { grows(gx + 3, ra, rb); issue16(bA, ra, rb); }
                dep(gx, a0, a1); flg(gx); }
            if (gb + 1 <= 64) { const int gx = gb + 1;
                unsigned long long a0 = ext8(bB, 0), a1 = ext8(bB, 1);
                if (gx + 3 <= 64) { grows(gx + 3, ra, rb); issue16(bB, ra, rb); }
                dep(gx, a0, a1); flg(gx); }
            if (gb + 2 <= 64) { const int gx = gb + 2;
                unsigned long long a0 = ext8(bC, 0), a1 = ext8(bC, 1);
                if (gx + 3 <= 64) { grows(gx + 3, ra, rb); issue16(bC, ra, rb); }
                dep(gx, a0, a1); flg(gx); }
        }
        return;   // producers done; no barriers below
    }

    // ============================ CONSUMER ============================
    // A^T fragments under pi: slot (kf,g,j2,e) holds A[p0+e][16mt+s],
    // p0 = 32kf + 16*(j2>>1) + 4g + 2*(j2&1).
    BFU Af[4][2];
#pragma unroll
    for (int mt = 0; mt < 4; ++mt)
#pragma unroll
        for (int kf = 0; kf < 2; ++kf)
#pragma unroll
            for (int j2 = 0; j2 < 4; ++j2) {
                int p0 = 32 * kf + 16 * (j2 >> 1) + 4 * g + 2 * (j2 & 1);
                Af[mt][kf].u[j2] = pk_rne(A[(size_t)p0 * S + mt * 16 + s],
                                          A[(size_t)(p0 + 1) * S + mt * 16 + s]);
            }

    BFU Bf[2];
#pragma unroll
    for (int kf = 0; kf < 2; ++kf)
#pragma unroll
        for (int jj = 0; jj < 4; ++jj) Bf[kf].u[jj] = 0x3F803F80u;  // 1.0 burn seed

    float S0v = 0.f, swv = 1.f;
    volatile unsigned* flj = &fl[j * NPACK];

    for (int p = 0; p < NPACK; ++p) {
        while (flj[p] == 0u) __builtin_amdgcn_s_sleep(2);   // pack-ready spin
        asm volatile("" ::: "memory");
        unsigned long long uv = myu[s * NPACK + p];   // this pack's o-bytes
#pragma unroll
        for (int k = 0; k < 8; ++k) {
            const int o = (int)(uv & 255ull);
            uv >>= 8;
            const float* br = &BmL[o * BMS];          // per-stream row, bank-phased
            f32x4 E[4], z0[4], z1[4];
#pragma unroll
            for (int mt = 0; mt < 4; ++mt) {
                E[mt] = *(const f32x4*)&br[mt * 16 + g * 4];
                f32x4 zr = {0.f, 0.f, 0.f, 0.f};
                z0[mt] = __builtin_amdgcn_mfma_f32_16x16x32_bf16(Af[mt][0].v, Bf[0].v, zr, 0, 0, 0);
                z1[mt] = __builtin_amdgcn_mfma_f32_16x16x32_bf16(Af[mt][1].v, Bf[1].v, zr, 0, 0, 0);
            }
            float w[4][4];
#pragma unroll
            for (int mt = 0; mt < 4; ++mt)
#pragma unroll
                for (int r = 0; r < 4; ++r) w[mt][r] = (z0[mt][r] + z1[mt][r]) * E[mt][r];
            if (p == BURNP && k == 0 && wq == 0) {    // exact t=0 init of chunk 0
                const bool c0 = (s == 0);
#pragma unroll
                for (int mt = 0; mt < 4; ++mt)
#pragma unroll
                    for (int r = 0; r < 4; ++r)
                        w[mt][r] = c0 ? ILds[mt * 16 + g * 4 + r] * E[mt][r] : w[mt][r];
            }
            if (k == 7 && (p == BURNP - 1 || p == NPACK - 1)) {  // mass (pre-scale)
                float swl = 0.f;
#pragma unroll
                for (int mt = 0; mt < 4; ++mt)
#pragma unroll
                    for (int r = 0; r < 4; ++r) swl += w[mt][r];
                swl += __shfl_xor(swl, 16);
                swl += __shfl_xor(swl, 32);
                swv = swl;
            }
            // zero-shuffle C->B under pi; constant 2^56 rescale at k==7
#pragma unroll
            for (int kf = 0; kf < 2; ++kf)
#pragma unroll
                for (int j2 = 0; j2 < 4; ++j2) {
                    int mt = 2 * kf + (j2 >> 1), pr = j2 & 1;
                    float v0 = w[mt][2 * pr], v1 = w[mt][2 * pr + 1];
                    if (k == 7) { v0 *= SCALEF; v1 *= SCALEF; }
                    Bf[kf].u[j2] = pk_trunc(v0, v1);
                }
        }
        if (p == BURNP - 1) {
            // exponents: burn mass carries 1*RB, final carries (NPACK-1)*RB
            const bool ch0 = (wq == 0) && (s == 0);
            S0v = ch0 ? ((float)(NPACK - 1 - BURNP) * RB)
                      : (__log2f(swv) + (float)(NPACK - BURNP) * RB);
        }
    }

    float tot = __log2f(swv) - S0v;
    // sum over the 16 streams (s-dim); g-lanes hold duplicates
    tot += __shfl_xor(tot, 1);
    tot += __shfl_xor(tot, 2);
    tot += __shfl_xor(tot, 4);
    tot += __shfl_xor(tot, 8);
    if (lane == 0)
        atomicAdd(out + seq, tot * 0.6931471805599453f);
}

extern "C" void kernel_launch(void* const* d_in, const int* in_sizes, int n_in,
                              void* d_out, int out_size, void* d_ws, size_t ws_size,
                              hipStream_t stream) {
    const float* x  = (const float*)d_in[0];   // [B,T,M] one-hot
    const float* I  = (const float*)d_in[1];   // [1,S]
    const float* A  = (const float*)d_in[2];   // [S,S]
    const float* Bm = (const float*)d_in[3];   // [M,S]
    float* out = (float*)d_out;                // [B,1]
    (void)d_ws; (void)ws_size;                 // workspace unused

    hipMemsetAsync(out, 0, (size_t)out_size * sizeof(float), stream);
    hmm_fused<<<BATCH * 2, 256, 0, stream>>>(x, I, A, Bm, out);  // 1024 blocks: 2048 producer + 2048 consumer waves
}